// Round 1
// baseline (126.888 us; speedup 1.0000x reference)
//
#include <hip/hip_runtime.h>
#include <math.h>

constexpr int BB = 2, NN = 4096, MM = 16384;
constexpr int TJ = 64, TI = 64;
constexpr unsigned INFBITS = 0x7F800000u;

__global__ __launch_bounds__(256) void init_ws_kernel(unsigned* ws, int n) {
    int i = blockIdx.x * 256 + threadIdx.x;
    if (i < n) ws[i] = INFBITS;
}

// Block: 256 threads = 16x16 (tx=j-group, ty=i-group). Each thread: 4 j's (fixed
// for whole kernel, raw pts in registers) x 4 i's per step. Block owns j-tile of
// 64, loops over all N sampled points (staged wholesale in LDS).
__global__ __launch_bounds__(256) void pair_kernel(
    const float* __restrict__ sampled,   // [BB][NN][4]
    const float* __restrict__ raw,       // [BB][MM][4]
    unsigned* __restrict__ rowmin,       // [BB][NN]  (float bits, atomicMin)
    float* __restrict__ colmin)          // [BB][MM]  (direct store)
{
    __shared__ float4 sArr[NN];          // 64 KB
    __shared__ float colred[16][TJ];     // 4 KB

    const int b  = blockIdx.y;
    const int j0 = blockIdx.x * TJ;
    const int tid = threadIdx.x;
    const int tx = tid & 15, ty = tid >> 4;

    const float4* sb = (const float4*)(sampled + (size_t)b * NN * 4);
    const float4* rb = (const float4*)(raw     + (size_t)b * MM * 4);

    for (int i = tid; i < NN; i += 256) sArr[i] = sb[i];

    float rxv[4], ryv[4], rzv[4];
#pragma unroll
    for (int r = 0; r < 4; ++r) {
        float4 rv = rb[j0 + tx * 4 + r];
        rxv[r] = rv.x; ryv[r] = rv.y; rzv[r] = rv.z;
    }

    const float INF = __uint_as_float(INFBITS);
    float cmin[4] = {INF, INF, INF, INF};

    __syncthreads();

    for (int istep = 0; istep < NN; istep += TI) {
        float rmin[4];
#pragma unroll
        for (int q = 0; q < 4; ++q) {
            float4 sv = sArr[istep + ty * 4 + q];
            float best = INF;
#pragma unroll
            for (int r = 0; r < 4; ++r) {
                float dx = sv.x - rxv[r];
                float dy = sv.y - ryv[r];
                float dz = sv.z - rzv[r];
                float sq = fmaf(dz, dz, fmaf(dy, dy, dx * dx));
                cmin[r] = fminf(cmin[r], sq);
                best    = fminf(best, sq);
            }
            rmin[q] = best;
        }
        // reduce row mins across the 16 tx lanes (within-wave, 16-lane groups)
#pragma unroll
        for (int m = 1; m < 16; m <<= 1) {
#pragma unroll
            for (int q = 0; q < 4; ++q)
                rmin[q] = fminf(rmin[q], __shfl_xor(rmin[q], m, 64));
        }
        if (tx == 0) {
#pragma unroll
            for (int q = 0; q < 4; ++q)
                atomicMin(&rowmin[(size_t)b * NN + istep + ty * 4 + q],
                          __float_as_uint(rmin[q]));
        }
    }

    // column mins: reduce across the 16 ty groups via LDS, direct store
#pragma unroll
    for (int r = 0; r < 4; ++r) colred[ty][tx * 4 + r] = cmin[r];
    __syncthreads();
    if (tid < TJ) {
        float v = colred[0][tid];
#pragma unroll
        for (int t = 1; t < 16; ++t) v = fminf(v, colred[t][tid]);
        colmin[(size_t)b * MM + j0 + tid] = v;
    }
}

__global__ __launch_bounds__(256) void final_kernel(
    const unsigned* __restrict__ rowmin,
    const float* __restrict__ colmin,
    float* __restrict__ out)
{
    __shared__ float ldsS[BB][2][4];
    __shared__ float ldsM[BB][4];
    const int tid = threadIdx.x;
    const int lane = tid & 63, w = tid >> 6;

    for (int b = 0; b < BB; ++b) {
        float sB = 0.f;
        for (int j = tid; j < MM; j += 256) sB += sqrtf(colmin[b * MM + j]);
        float sF = 0.f, mF = 0.f;
        for (int i = tid; i < NN; i += 256) {
            float d = sqrtf(__uint_as_float(rowmin[b * NN + i]));
            sF += d;
            mF = fmaxf(mF, d);
        }
        for (int m = 1; m < 64; m <<= 1) {
            sB += __shfl_xor(sB, m, 64);
            sF += __shfl_xor(sF, m, 64);
            mF = fmaxf(mF, __shfl_xor(mF, m, 64));
        }
        if (lane == 0) { ldsS[b][0][w] = sB; ldsS[b][1][w] = sF; ldsM[b][w] = mF; }
    }
    __syncthreads();
    if (tid == 0) {
        float total = 0.f;
        for (int b = 0; b < BB; ++b) {
            float sB = ldsS[b][0][0] + ldsS[b][0][1] + ldsS[b][0][2] + ldsS[b][0][3];
            float sF = ldsS[b][1][0] + ldsS[b][1][1] + ldsS[b][1][2] + ldsS[b][1][3];
            float mF = fmaxf(fmaxf(ldsM[b][0], ldsM[b][1]),
                             fmaxf(ldsM[b][2], ldsM[b][3]));
            total += 5.f * (sB / (float)MM) + sF / (float)NN + mF;
        }
        *out = total / (float)BB;
    }
}

extern "C" void kernel_launch(void* const* d_in, const int* in_sizes, int n_in,
                              void* d_out, int out_size, void* d_ws, size_t ws_size,
                              hipStream_t stream) {
    const float* sampled = (const float*)d_in[0];
    const float* raw     = (const float*)d_in[1];
    unsigned* rowmin = (unsigned*)d_ws;
    float*    colmin = (float*)((char*)d_ws + (size_t)BB * NN * sizeof(unsigned));
    float*    out    = (float*)d_out;

    const int ninit = BB * NN + BB * MM;
    init_ws_kernel<<<(ninit + 255) / 256, 256, 0, stream>>>((unsigned*)d_ws, ninit);
    pair_kernel<<<dim3(MM / TJ, BB), 256, 0, stream>>>(sampled, raw, rowmin, colmin);
    final_kernel<<<1, 256, 0, stream>>>(rowmin, colmin, out);
}

// Round 2
// 53.508 us; speedup vs baseline: 2.3714x; 2.3714x over previous
//
#include <hip/hip_runtime.h>
#include <math.h>

constexpr int BB = 2, NN = 4096, MM = 16384;
constexpr int TJ = 64;                    // j-tile per block (8 tx * 8 regs)
constexpr int NCH = 4, CH = NN / NCH;     // i-chunk per block
constexpr unsigned INFBITS = 0x7F800000u;

__global__ __launch_bounds__(256) void init_ws_kernel(unsigned* ws, int n) {
    int i = blockIdx.x * 256 + threadIdx.x;
    if (i < n) ws[i] = INFBITS;
}

// grid (MM/TJ, NCH, BB); block 256 = 8 tx (8 j's each) x 32 ty (2 i's per step)
__global__ __launch_bounds__(256, 4) void pair_kernel(
    const float* __restrict__ sampled,   // [BB][NN][4]
    const float* __restrict__ raw,       // [BB][MM][4]
    unsigned* __restrict__ rowmin,       // [BB][NN]  float bits, atomicMin
    unsigned* __restrict__ colmin)       // [BB][MM]  float bits, atomicMin
{
    __shared__ float4 sArr[CH];          // 16 KB, .w = |s|^2
    __shared__ float colred[4][TJ];      // 1 KB

    const int b  = blockIdx.z;
    const int i00 = blockIdx.y * CH;
    const int j0 = blockIdx.x * TJ;
    const int tid = threadIdx.x;
    const int tx = tid & 7, ty = tid >> 3;

    const float4* sb = (const float4*)sampled + (size_t)b * NN + i00;
    const float4* rb = (const float4*)raw     + (size_t)b * MM;

    for (int i = tid; i < CH; i += 256) {
        float4 v = sb[i];
        v.w = fmaf(v.z, v.z, fmaf(v.y, v.y, v.x * v.x));
        sArr[i] = v;
    }

    // 8 raw points per thread, kept for the whole kernel
    float rx[8], ry[8], rz[8], rw[8];
#pragma unroll
    for (int r = 0; r < 8; ++r) {
        float4 v = rb[j0 + tx * 8 + r];
        rw[r] = fmaf(v.z, v.z, fmaf(v.y, v.y, v.x * v.x));
        rx[r] = -2.f * v.x; ry[r] = -2.f * v.y; rz[r] = -2.f * v.z;
    }

    const float INF = __uint_as_float(INFBITS);
    float cmin[8] = {INF, INF, INF, INF, INF, INF, INF, INF};

    __syncthreads();

    for (int i0 = 0; i0 < CH; i0 += 64) {
        float rmin[2];
#pragma unroll
        for (int q = 0; q < 2; ++q) {
            float4 sv = sArr[i0 + ty * 2 + q];
            float best = INF;
#pragma unroll
            for (int r = 0; r < 8; ++r) {
                float a = sv.w + rw[r];
                a = fmaf(sv.x, rx[r], a);
                a = fmaf(sv.y, ry[r], a);
                a = fmaf(sv.z, rz[r], a);
                cmin[r] = fminf(cmin[r], a);
                best    = fminf(best, a);
            }
            rmin[q] = best;
        }
        // reduce across the 8 tx lanes (same ty group, within wave)
#pragma unroll
        for (int m = 1; m < 8; m <<= 1) {
#pragma unroll
            for (int q = 0; q < 2; ++q)
                rmin[q] = fminf(rmin[q], __shfl_xor(rmin[q], m, 64));
        }
        if (tx == 0) {
#pragma unroll
            for (int q = 0; q < 2; ++q)
                atomicMin(&rowmin[(size_t)b * NN + i00 + i0 + ty * 2 + q],
                          __float_as_uint(fmaxf(rmin[q], 0.f)));
        }
    }

    // column mins: reduce across ty within wave (masks 8,16,32), then across waves
#pragma unroll
    for (int m = 8; m < 64; m <<= 1) {
#pragma unroll
        for (int r = 0; r < 8; ++r)
            cmin[r] = fminf(cmin[r], __shfl_xor(cmin[r], m, 64));
    }
    const int lane = tid & 63, w = tid >> 6;
    if (lane < 8) {
#pragma unroll
        for (int r = 0; r < 8; ++r) colred[w][lane * 8 + r] = cmin[r];
    }
    __syncthreads();
    if (tid < TJ) {
        float v = fminf(fminf(colred[0][tid], colred[1][tid]),
                        fminf(colred[2][tid], colred[3][tid]));
        atomicMin(&colmin[(size_t)b * MM + j0 + tid],
                  __float_as_uint(fmaxf(v, 0.f)));
    }
}

// 64 blocks: b = k>>5, slice s = k&31
__global__ __launch_bounds__(256) void reduce1_kernel(
    const unsigned* __restrict__ rowmin,
    const unsigned* __restrict__ colmin,
    float* __restrict__ part)
{
    const int k = blockIdx.x, b = k >> 5, s = k & 31;
    const int tid = threadIdx.x;
    constexpr int CS = MM / 32, RS = NN / 32;

    float sB = 0.f;
    const unsigned* cm = colmin + (size_t)b * MM + s * CS;
    for (int j = tid; j < CS; j += 256) sB += sqrtf(__uint_as_float(cm[j]));

    float sF = 0.f, mF = 0.f;
    const unsigned* rm = rowmin + (size_t)b * NN + s * RS;
    for (int i = tid; i < RS; i += 256) {
        float d = sqrtf(__uint_as_float(rm[i]));
        sF += d; mF = fmaxf(mF, d);
    }
    for (int m = 1; m < 64; m <<= 1) {
        sB += __shfl_xor(sB, m, 64);
        sF += __shfl_xor(sF, m, 64);
        mF = fmaxf(mF, __shfl_xor(mF, m, 64));
    }
    __shared__ float red[3][4];
    const int lane = tid & 63, w = tid >> 6;
    if (lane == 0) { red[0][w] = sB; red[1][w] = sF; red[2][w] = mF; }
    __syncthreads();
    if (tid == 0) {
        sB = red[0][0] + red[0][1] + red[0][2] + red[0][3];
        sF = red[1][0] + red[1][1] + red[1][2] + red[1][3];
        mF = fmaxf(fmaxf(red[2][0], red[2][1]), fmaxf(red[2][2], red[2][3]));
        part[k * 3 + 0] = sB; part[k * 3 + 1] = sF; part[k * 3 + 2] = mF;
    }
}

__global__ void reduce2_kernel(const float* __restrict__ part,
                               float* __restrict__ out)
{
    const int lane = threadIdx.x;   // 64 threads; lanes 0..31 = b0, 32..63 = b1
    float sB = part[lane * 3 + 0];
    float sF = part[lane * 3 + 1];
    float mF = part[lane * 3 + 2];
    for (int m = 1; m < 32; m <<= 1) {
        sB += __shfl_xor(sB, m, 64);
        sF += __shfl_xor(sF, m, 64);
        mF = fmaxf(mF, __shfl_xor(mF, m, 64));
    }
    float oB = __shfl_xor(sB, 32, 64);
    float oF = __shfl_xor(sF, 32, 64);
    float oM = __shfl_xor(mF, 32, 64);
    if (lane == 0) {
        float l0 = 5.f * sB / (float)MM + sF / (float)NN + mF;
        float l1 = 5.f * oB / (float)MM + oF / (float)NN + oM;
        *out = 0.5f * (l0 + l1);
    }
}

extern "C" void kernel_launch(void* const* d_in, const int* in_sizes, int n_in,
                              void* d_out, int out_size, void* d_ws, size_t ws_size,
                              hipStream_t stream) {
    const float* sampled = (const float*)d_in[0];
    const float* raw     = (const float*)d_in[1];
    unsigned* rowmin = (unsigned*)d_ws;
    unsigned* colmin = rowmin + (size_t)BB * NN;
    float*    part   = (float*)(colmin + (size_t)BB * MM);
    float*    out    = (float*)d_out;

    const int ninit = BB * NN + BB * MM;
    init_ws_kernel<<<(ninit + 255) / 256, 256, 0, stream>>>((unsigned*)d_ws, ninit);
    pair_kernel<<<dim3(MM / TJ, NCH, BB), 256, 0, stream>>>(sampled, raw, rowmin, colmin);
    reduce1_kernel<<<64, 256, 0, stream>>>(rowmin, colmin, part);
    reduce2_kernel<<<1, 64, 0, stream>>>(part, out);
}